// Round 2
// baseline (723.267 us; speedup 1.0000x reference)
//
#include <hip/hip_runtime.h>
#include <cstdint>
#include <cstddef>

typedef _Float16 f16;
typedef _Float16 f16x8 __attribute__((ext_vector_type(8)));
typedef float f32x4 __attribute__((ext_vector_type(4)));

#define DEVI __device__ __forceinline__

DEVI void gload_lds16(const void* g, void* l) {
  __builtin_amdgcn_global_load_lds(
      (const __attribute__((address_space(1))) void*)g,
      (__attribute__((address_space(3))) void*)l, 16, 0, 0);
}

// ---------------- f32 -> f16 convert, 8 elems/thread ----------------
__global__ void k_cvt(const float* __restrict__ in, f16* __restrict__ out, int n) {
  int i = (blockIdx.x * 256 + threadIdx.x) * 8;
  if (i >= n) return;
  const float4* p = reinterpret_cast<const float4*>(in + i);
  float4 a = p[0], b = p[1];
  f16x8 o;
  o[0] = (f16)a.x; o[1] = (f16)a.y; o[2] = (f16)a.z; o[3] = (f16)a.w;
  o[4] = (f16)b.x; o[5] = (f16)b.y; o[6] = (f16)b.z; o[7] = (f16)b.w;
  *reinterpret_cast<f16x8*>(out + i) = o;
}

// ---------------- GEMM: C[M,N] = A[M,K] * B[N,K]^T (both K-contiguous) ----
// 128x128 tile, BK=64, 4 waves (2x2), 16x16x32 f16 MFMA, global_load_lds,
// XOR swizzle (16B unit ^= row&7) for 2-way-max LDS bank conflicts.
template<int OUTF32>
__global__ __launch_bounds__(256) void k_gemm(
    const f16* __restrict__ A,
    const f16* __restrict__ B0, const f16* __restrict__ B1, const f16* __restrict__ B2,
    void* __restrict__ C0, void* __restrict__ C1, void* __restrict__ C2) {
  constexpr int K = 1024, N = 1024;
  __shared__ f16 As[128 * 64];
  __shared__ f16 Bs[128 * 64];
  const f16* B = (blockIdx.z == 0) ? B0 : ((blockIdx.z == 1) ? B1 : B2);
  void* C = (blockIdx.z == 0) ? C0 : ((blockIdx.z == 1) ? C1 : C2);
  const int tid = threadIdx.x;
  const int lane = tid & 63;
  const int wave = tid >> 6;
  const int wr = wave >> 1, wc = wave & 1;
  const int l15 = lane & 15, l4 = lane >> 4;
  const int m0 = blockIdx.y * 128, n0 = blockIdx.x * 128;
  const int srow = tid >> 3, su = tid & 7;

  f32x4 acc[4][4] = {};

  for (int kt = 0; kt < K; kt += 64) {
    __syncthreads();
#pragma unroll
    for (int q = 0; q < 4; ++q) {
      int r = q * 32 + srow;
      int ce = (su ^ (r & 7)) * 8;  // swizzled source column (elements)
      gload_lds16(A + (size_t)(m0 + r) * K + kt + ce,
                  (char*)As + (q * 256 + (tid & 192)) * 16);
    }
#pragma unroll
    for (int q = 0; q < 4; ++q) {
      int r = q * 32 + srow;
      int ce = (su ^ (r & 7)) * 8;
      gload_lds16(B + (size_t)(n0 + r) * K + kt + ce,
                  (char*)Bs + (q * 256 + (tid & 192)) * 16);
    }
    __syncthreads();
#pragma unroll
    for (int kk = 0; kk < 2; ++kk) {
      f16x8 af[4], bf[4];
#pragma unroll
      for (int mi = 0; mi < 4; ++mi) {
        int r = wr * 64 + mi * 16 + l15;
        int u = (kk * 4 + l4) ^ (r & 7);
        af[mi] = *reinterpret_cast<const f16x8*>((const char*)As + r * 128 + u * 16);
      }
#pragma unroll
      for (int ni = 0; ni < 4; ++ni) {
        int r = wc * 64 + ni * 16 + l15;
        int u = (kk * 4 + l4) ^ (r & 7);
        bf[ni] = *reinterpret_cast<const f16x8*>((const char*)Bs + r * 128 + u * 16);
      }
#pragma unroll
      for (int mi = 0; mi < 4; ++mi)
#pragma unroll
        for (int ni = 0; ni < 4; ++ni)
          acc[mi][ni] = __builtin_amdgcn_mfma_f32_16x16x32_f16(af[mi], bf[ni], acc[mi][ni], 0, 0, 0);
    }
  }
  // epilogue: D layout col=lane&15, row=(lane>>4)*4+reg
#pragma unroll
  for (int mi = 0; mi < 4; ++mi)
#pragma unroll
    for (int ni = 0; ni < 4; ++ni)
#pragma unroll
      for (int r = 0; r < 4; ++r) {
        int row = m0 + wr * 64 + mi * 16 + l4 * 4 + r;
        int col = n0 + wc * 64 + ni * 16 + l15;
        if (OUTF32)
          ((float*)C)[(size_t)row * N + col] = acc[mi][ni][r];
        else
          ((f16*)C)[(size_t)row * N + col] = (f16)acc[mi][ni][r];
      }
}

// ---------------- RoPE in-place on Q and K ----------------
// thread per (b, s, h, pair t). skip_phase_rope: rows s<E untouched, pos=s-E.
__global__ void k_rope(f16* __restrict__ Q, f16* __restrict__ Kk,
                       const int* __restrict__ pE, const int* __restrict__ pSkip) {
  int idx = blockIdx.x * 256 + threadIdx.x;  // 4M total
  int t = idx & 31;
  int h = (idx >> 5) & 15;
  int s = (idx >> 9) & 2047;
  int b = idx >> 20;
  int E = *pE, skip = *pSkip;
  int p;
  if (skip) { if (s < E) return; p = s - E; } else { p = s; }
  float inv_freq = powf(10000.0f, -(float)t / 32.0f);  // theta^(-2t/64)
  float ang = (float)p * inv_freq;
  float sn, cs;
  sincosf(ang, &sn, &cs);
  size_t base = ((size_t)((b * 2048 + s) * 16 + h)) * 64 + 2 * t;
  union UU { unsigned u; f16 h2[2]; };
  UU qv; qv.u = *reinterpret_cast<const unsigned*>(Q + base);
  float q0 = (float)qv.h2[0], q1 = (float)qv.h2[1];
  qv.h2[0] = (f16)(q0 * cs - q1 * sn);
  qv.h2[1] = (f16)(q1 * cs + q0 * sn);
  *reinterpret_cast<unsigned*>(Q + base) = qv.u;
  UU kv; kv.u = *reinterpret_cast<const unsigned*>(Kk + base);
  float k0 = (float)kv.h2[0], k1 = (float)kv.h2[1];
  kv.h2[0] = (f16)(k0 * cs - k1 * sn);
  kv.h2[1] = (f16)(k1 * cs + k0 * sn);
  *reinterpret_cast<unsigned*>(Kk + base) = kv.u;
}

// ---------------- V transpose: (b,s,h*64+d) -> (bh, d, s) ----------------
__global__ __launch_bounds__(256) void k_vtrans(const f16* __restrict__ Vf, f16* __restrict__ Vt) {
  __shared__ f16 tile[64 * 64];
  const int sb = blockIdx.x, bh = blockIdx.y;
  const int b = bh >> 4, h = bh & 15;
  const int tid = threadIdx.x;
#pragma unroll
  for (int it = 0; it < 2; ++it) {
    int i = it * 32 + (tid >> 3);      // s-row within tile
    int u = tid & 7;                   // 8-elem unit (d)
    f16x8 v = *reinterpret_cast<const f16x8*>(
        Vf + ((size_t)(b * 2048 + sb * 64 + i)) * 1024 + h * 64 + u * 8);
    int us = u ^ (i & 7);
    *reinterpret_cast<f16x8*>(&tile[i * 64 + us * 8]) = v;
  }
  __syncthreads();
  const int j = tid >> 2;            // d-row (0..63)
  const int c0 = (tid & 3) * 16;     // s-chunk
  f16 vals[16];
#pragma unroll
  for (int k = 0; k < 16; ++k) {
    int i = c0 + k;
    vals[k] = tile[i * 64 + (((j >> 3) ^ (i & 7)) << 3) + (j & 7)];
  }
  f16x8 o0, o1;
#pragma unroll
  for (int k = 0; k < 8; ++k) { o0[k] = vals[k]; o1[k] = vals[8 + k]; }
  f16* dst = Vt + (size_t)bh * 131072 + (size_t)j * 2048 + sb * 64 + c0;
  *reinterpret_cast<f16x8*>(dst) = o0;
  *reinterpret_cast<f16x8*>(dst + 8) = o1;
}

// ---------------- flash attention ----------------
// grid (S/64, B*H), 4 waves x 16 q-rows. Q stationary; K,V from global (L2-shared);
// online softmax; P re-layout via per-wave swizzled LDS.
__global__ __launch_bounds__(256) void k_attn(
    const f16* __restrict__ Q, const f16* __restrict__ Kg, const f16* __restrict__ Vt,
    const int* __restrict__ amask, const int* __restrict__ pE,
    f16* __restrict__ AO) {
  __shared__ f16 P_lds[4][16 * 64];
  const int qb = blockIdx.x, bh = blockIdx.y;
  const int b = bh >> 4, h = bh & 15;
  const int tid = threadIdx.x;
  const int wave = tid >> 6, lane = tid & 63;
  const int l15 = lane & 15, l4 = lane >> 4;
  const int E = *pE;
  const int qrow0 = qb * 64 + wave * 16;

  f16x8 qf0, qf1;
  {
    const f16* qp = Q + ((size_t)(b * 2048 + qrow0 + l15)) * 1024 + h * 64;
    qf0 = *reinterpret_cast<const f16x8*>(qp + l4 * 8);
    qf1 = *reinterpret_cast<const f16x8*>(qp + 32 + l4 * 8);
  }
  f32x4 acc[4] = {};
  float mst[4] = {-1e30f, -1e30f, -1e30f, -1e30f};
  float lst[4] = {0.f, 0.f, 0.f, 0.f};

  int nkv = qb + 1;                 // causal blocks
  int ekv = (E + 63) >> 6;          // phase-visible blocks
  if (ekv > nkv) nkv = ekv;
  if (nkv > 32) nkv = 32;

  for (int jb = 0; jb < nkv; ++jb) {
    f32x4 sc[4];
#pragma unroll
    for (int jt = 0; jt < 4; ++jt) {
      const f16* kp = Kg + ((size_t)(b * 2048 + jb * 64 + jt * 16 + l15)) * 1024 + h * 64;
      f16x8 kf0 = *reinterpret_cast<const f16x8*>(kp + l4 * 8);
      f16x8 kf1 = *reinterpret_cast<const f16x8*>(kp + 32 + l4 * 8);
      f32x4 s = {};
      s = __builtin_amdgcn_mfma_f32_16x16x32_f16(qf0, kf0, s, 0, 0, 0);
      s = __builtin_amdgcn_mfma_f32_16x16x32_f16(qf1, kf1, s, 0, 0, 0);
      sc[jt] = s;
    }
    // scale + mask: visible = (j<=i) || (j<E), and attention_mask col (int32!)
#pragma unroll
    for (int jt = 0; jt < 4; ++jt) {
      int jcol = jb * 64 + jt * 16 + l15;
      bool colok = (amask[b * 2048 + jcol] != 0);
#pragma unroll
      for (int r = 0; r < 4; ++r) {
        int irow = qrow0 + l4 * 4 + r;
        bool vis = colok && ((jcol <= irow) || (jcol < E));
        sc[jt][r] = vis ? sc[jt][r] * 0.125f : -1e30f;
      }
    }
    // online softmax per row r (rows live across 16-lane groups)
#pragma unroll
    for (int r = 0; r < 4; ++r) {
      float m = fmaxf(fmaxf(sc[0][r], sc[1][r]), fmaxf(sc[2][r], sc[3][r]));
#pragma unroll
      for (int off = 1; off < 16; off <<= 1) m = fmaxf(m, __shfl_xor(m, off, 64));
      float mnew = fmaxf(mst[r], m);
      float alpha = (mnew <= -1e29f) ? 0.f : __expf(mst[r] - mnew);
      float psum = 0.f;
      int prow = l4 * 4 + r;
#pragma unroll
      for (int jt = 0; jt < 4; ++jt) {
        float sv = sc[jt][r];
        float p = (sv <= -1e29f) ? 0.f : __expf(sv - mnew);
        psum += p;
        int pcol = jt * 16 + l15;
        P_lds[wave][prow * 64 + (((pcol >> 3) ^ (prow & 7)) << 3) + (pcol & 7)] = (f16)p;
      }
#pragma unroll
      for (int off = 1; off < 16; off <<= 1) psum += __shfl_xor(psum, off, 64);
      lst[r] = lst[r] * alpha + psum;
      mst[r] = mnew;
#pragma unroll
      for (int dt = 0; dt < 4; ++dt) acc[dt][r] *= alpha;
    }
    __syncthreads();  // P writes (cross-lane) -> P reads
    f16x8 pa0 = *reinterpret_cast<const f16x8*>(&P_lds[wave][l15 * 64 + ((l4 ^ (l15 & 7)) << 3)]);
    f16x8 pa1 = *reinterpret_cast<const f16x8*>(&P_lds[wave][l15 * 64 + (((4 + l4) ^ (l15 & 7)) << 3)]);
#pragma unroll
    for (int dt = 0; dt < 4; ++dt) {
      const f16* vp = Vt + (size_t)bh * 131072 + (size_t)(dt * 16 + l15) * 2048 + jb * 64;
      f16x8 vb0 = *reinterpret_cast<const f16x8*>(vp + l4 * 8);
      f16x8 vb1 = *reinterpret_cast<const f16x8*>(vp + 32 + l4 * 8);
      acc[dt] = __builtin_amdgcn_mfma_f32_16x16x32_f16(pa0, vb0, acc[dt], 0, 0, 0);
      acc[dt] = __builtin_amdgcn_mfma_f32_16x16x32_f16(pa1, vb1, acc[dt], 0, 0, 0);
    }
    __syncthreads();  // protect P_lds reuse next iteration
  }
#pragma unroll
  for (int r = 0; r < 4; ++r) {
    float inv = 1.0f / lst[r];
    int row = qrow0 + l4 * 4 + r;
    f16* op = AO + ((size_t)(b * 2048 + row)) * 1024 + h * 64;
#pragma unroll
    for (int dt = 0; dt < 4; ++dt)
      op[dt * 16 + l15] = (f16)(acc[dt][r] * inv);
  }
}

// ---------------- launcher ----------------
extern "C" void kernel_launch(void* const* d_in, const int* in_sizes, int n_in,
                              void* d_out, int out_size, void* d_ws, size_t ws_size,
                              hipStream_t stream) {
  const float* x  = (const float*)d_in[0];
  const float* Wq = (const float*)d_in[1];
  const float* Wk = (const float*)d_in[2];
  const float* Wv = (const float*)d_in[3];
  const float* Wo = (const float*)d_in[4];
  const int* amask = (const int*)d_in[5];   // bool -> int32 per harness convention
  const int* pE    = (const int*)d_in[6];
  const int* pSkip = (const int*)d_in[7];

  char* ws = (char*)d_ws;
  f16* xb  = (f16*)(ws);                    // 16 MB, reused as AO after QKV GEMM
  f16* Wqb = (f16*)(ws + (16u << 20));
  f16* Wkb = (f16*)(ws + (18u << 20));
  f16* Wvb = (f16*)(ws + (20u << 20));
  f16* Wob = (f16*)(ws + (22u << 20));
  f16* Qf  = (f16*)(ws + (24u << 20));
  f16* Kf  = (f16*)(ws + (40u << 20));
  f16* Vf  = (f16*)(ws + (56u << 20));
  f16* Vt  = (f16*)(ws + (72u << 20));      // total 88 MB
  f16* AO  = xb;

  // converts
  k_cvt<<<4096, 256, 0, stream>>>(x, xb, 8388608);
  k_cvt<<<512, 256, 0, stream>>>(Wq, Wqb, 1048576);
  k_cvt<<<512, 256, 0, stream>>>(Wk, Wkb, 1048576);
  k_cvt<<<512, 256, 0, stream>>>(Wv, Wvb, 1048576);
  k_cvt<<<512, 256, 0, stream>>>(Wo, Wob, 1048576);
  // QKV projections (fused over grid.z)
  k_gemm<0><<<dim3(8, 64, 3), 256, 0, stream>>>(xb, Wqb, Wkb, Wvb, Qf, Kf, Vf);
  // RoPE in place on Q, K
  k_rope<<<16384, 256, 0, stream>>>(Qf, Kf, pE, pSkip);
  // V transpose for PV MFMA
  k_vtrans<<<dim3(32, 64), 256, 0, stream>>>(Vf, Vt);
  // attention
  k_attn<<<dim3(32, 64), 256, 0, stream>>>(Qf, Kf, Vt, amask, pE, AO);
  // output projection -> fp32 d_out
  k_gemm<1><<<dim3(8, 64, 1), 256, 0, stream>>>(AO, Wob, Wob, Wob, d_out, d_out, d_out);
}

// Round 3
// 452.563 us; speedup vs baseline: 1.5982x; 1.5982x over previous
//
#include <hip/hip_runtime.h>
#include <cstdint>
#include <cstddef>

typedef _Float16 f16;
typedef _Float16 f16x8 __attribute__((ext_vector_type(8)));
typedef float f32x4 __attribute__((ext_vector_type(4)));

#define DEVI __device__ __forceinline__

DEVI void gload_lds16(const void* g, void* l) {
  __builtin_amdgcn_global_load_lds(
      (const __attribute__((address_space(1))) void*)g,
      (__attribute__((address_space(3))) void*)l, 16, 0, 0);
}

// ---------------- f32 -> f16 convert, 8 elems/thread ----------------
__global__ void k_cvt(const float* __restrict__ in, f16* __restrict__ out, int n) {
  int i = (blockIdx.x * 256 + threadIdx.x) * 8;
  if (i >= n) return;
  const float4* p = reinterpret_cast<const float4*>(in + i);
  float4 a = p[0], b = p[1];
  f16x8 o;
  o[0] = (f16)a.x; o[1] = (f16)a.y; o[2] = (f16)a.z; o[3] = (f16)a.w;
  o[4] = (f16)b.x; o[5] = (f16)b.y; o[6] = (f16)b.z; o[7] = (f16)b.w;
  *reinterpret_cast<f16x8*>(out + i) = o;
}

// ---------------- GEMM: C[M,N] = A[M,K] * B[N,K]^T ----------------
template<int OUTF32>
__global__ __launch_bounds__(256) void k_gemm(
    const f16* __restrict__ A,
    const f16* __restrict__ B0, const f16* __restrict__ B1, const f16* __restrict__ B2,
    void* __restrict__ C0, void* __restrict__ C1, void* __restrict__ C2) {
  constexpr int K = 1024, N = 1024;
  __shared__ f16 As[128 * 64];
  __shared__ f16 Bs[128 * 64];
  const f16* B = (blockIdx.z == 0) ? B0 : ((blockIdx.z == 1) ? B1 : B2);
  void* C = (blockIdx.z == 0) ? C0 : ((blockIdx.z == 1) ? C1 : C2);
  const int tid = threadIdx.x;
  const int lane = tid & 63;
  const int wave = tid >> 6;
  const int wr = wave >> 1, wc = wave & 1;
  const int l15 = lane & 15, l4 = lane >> 4;
  const int m0 = blockIdx.y * 128, n0 = blockIdx.x * 128;
  const int srow = tid >> 3, su = tid & 7;

  f32x4 acc[4][4] = {};

  for (int kt = 0; kt < K; kt += 64) {
    __syncthreads();
#pragma unroll
    for (int q = 0; q < 4; ++q) {
      int r = q * 32 + srow;
      int ce = (su ^ (r & 7)) * 8;
      gload_lds16(A + (size_t)(m0 + r) * K + kt + ce,
                  (char*)As + (q * 256 + (tid & 192)) * 16);
    }
#pragma unroll
    for (int q = 0; q < 4; ++q) {
      int r = q * 32 + srow;
      int ce = (su ^ (r & 7)) * 8;
      gload_lds16(B + (size_t)(n0 + r) * K + kt + ce,
                  (char*)Bs + (q * 256 + (tid & 192)) * 16);
    }
    __syncthreads();
#pragma unroll
    for (int kk = 0; kk < 2; ++kk) {
      f16x8 af[4], bf[4];
#pragma unroll
      for (int mi = 0; mi < 4; ++mi) {
        int r = wr * 64 + mi * 16 + l15;
        int u = (kk * 4 + l4) ^ (r & 7);
        af[mi] = *reinterpret_cast<const f16x8*>((const char*)As + r * 128 + u * 16);
      }
#pragma unroll
      for (int ni = 0; ni < 4; ++ni) {
        int r = wc * 64 + ni * 16 + l15;
        int u = (kk * 4 + l4) ^ (r & 7);
        bf[ni] = *reinterpret_cast<const f16x8*>((const char*)Bs + r * 128 + u * 16);
      }
#pragma unroll
      for (int mi = 0; mi < 4; ++mi)
#pragma unroll
        for (int ni = 0; ni < 4; ++ni)
          acc[mi][ni] = __builtin_amdgcn_mfma_f32_16x16x32_f16(af[mi], bf[ni], acc[mi][ni], 0, 0, 0);
    }
  }
#pragma unroll
  for (int mi = 0; mi < 4; ++mi)
#pragma unroll
    for (int ni = 0; ni < 4; ++ni)
#pragma unroll
      for (int r = 0; r < 4; ++r) {
        int row = m0 + wr * 64 + mi * 16 + l4 * 4 + r;
        int col = n0 + wc * 64 + ni * 16 + l15;
        if (OUTF32)
          ((float*)C)[(size_t)row * N + col] = acc[mi][ni][r];
        else
          ((f16*)C)[(size_t)row * N + col] = (f16)acc[mi][ni][r];
      }
}

// ---------------- RoPE in-place on Q and K ----------------
__global__ void k_rope(f16* __restrict__ Q, f16* __restrict__ Kk,
                       const int* __restrict__ pE, const int* __restrict__ pSkip) {
  int idx = blockIdx.x * 256 + threadIdx.x;
  int t = idx & 31;
  int h = (idx >> 5) & 15;
  int s = (idx >> 9) & 2047;
  int b = idx >> 20;
  int E = *pE, skip = *pSkip;
  int p;
  if (skip) { if (s < E) return; p = s - E; } else { p = s; }
  float inv_freq = powf(10000.0f, -(float)t / 32.0f);
  float ang = (float)p * inv_freq;
  float sn, cs;
  sincosf(ang, &sn, &cs);
  size_t base = ((size_t)((b * 2048 + s) * 16 + h)) * 64 + 2 * t;
  union UU { unsigned u; f16 h2[2]; };
  UU qv; qv.u = *reinterpret_cast<const unsigned*>(Q + base);
  float q0 = (float)qv.h2[0], q1 = (float)qv.h2[1];
  qv.h2[0] = (f16)(q0 * cs - q1 * sn);
  qv.h2[1] = (f16)(q1 * cs + q0 * sn);
  *reinterpret_cast<unsigned*>(Q + base) = qv.u;
  UU kv; kv.u = *reinterpret_cast<const unsigned*>(Kk + base);
  float k0 = (float)kv.h2[0], k1 = (float)kv.h2[1];
  kv.h2[0] = (f16)(k0 * cs - k1 * sn);
  kv.h2[1] = (f16)(k1 * cs + k0 * sn);
  *reinterpret_cast<unsigned*>(Kk + base) = kv.u;
}

// ---------------- V transpose: (b,s,h*64+d) -> (bh, d, s) ----------------
__global__ __launch_bounds__(256) void k_vtrans(const f16* __restrict__ Vf, f16* __restrict__ Vt) {
  __shared__ f16 tile[64 * 64];
  const int sb = blockIdx.x, bh = blockIdx.y;
  const int b = bh >> 4, h = bh & 15;
  const int tid = threadIdx.x;
#pragma unroll
  for (int it = 0; it < 2; ++it) {
    int i = it * 32 + (tid >> 3);
    int u = tid & 7;
    f16x8 v = *reinterpret_cast<const f16x8*>(
        Vf + ((size_t)(b * 2048 + sb * 64 + i)) * 1024 + h * 64 + u * 8);
    int us = u ^ (i & 7);
    *reinterpret_cast<f16x8*>(&tile[i * 64 + us * 8]) = v;
  }
  __syncthreads();
  const int j = tid >> 2;
  const int c0 = (tid & 3) * 16;
  f16 vals[16];
#pragma unroll
  for (int k = 0; k < 16; ++k) {
    int i = c0 + k;
    vals[k] = tile[i * 64 + (((j >> 3) ^ (i & 7)) << 3) + (j & 7)];
  }
  f16x8 o0, o1;
#pragma unroll
  for (int k = 0; k < 8; ++k) { o0[k] = vals[k]; o1[k] = vals[8 + k]; }
  f16* dst = Vt + (size_t)bh * 131072 + (size_t)j * 2048 + sb * 64 + c0;
  *reinterpret_cast<f16x8*>(dst) = o0;
  *reinterpret_cast<f16x8*>(dst + 8) = o1;
}

// ---------------- flash attention (barrier-free, prefetched) ----------------
// 1-D grid 2048 = (bh, qb) with bijective XCD swizzle (8 bh-groups per XCD for
// K/V L2 residence) and heavy-first qb ordering (causal tail balance).
// 4 independent waves x 16 q-rows; NO __syncthreads: P_lds is wave-private,
// guarded by in-wave s_waitcnt lgkmcnt(0). Next K-tile prefetched into regs;
// V/amask loads issued before softmax so latency hides under it.
__global__ __launch_bounds__(256) void k_attn(
    const f16* __restrict__ Q, const f16* __restrict__ Kg, const f16* __restrict__ Vt,
    const int* __restrict__ amask, const int* __restrict__ pE,
    f16* __restrict__ AO) {
  __shared__ f16 P_lds[4][2][16 * 64];
  const int lid = (blockIdx.x & 7) * 256 + (blockIdx.x >> 3);  // XCD swizzle (2048%8==0)
  const int bh = lid >> 5;
  const int qb = 31 - (lid & 31);                              // heavy blocks first
  const int b = bh >> 4, h = bh & 15;
  const int tid = threadIdx.x;
  const int wave = tid >> 6, lane = tid & 63;
  const int l15 = lane & 15, l4 = lane >> 4;
  const int E = *pE;
  const int qrow0 = qb * 64 + wave * 16;
  constexpr float SCALE = 0.125f * 1.44269504088896f;  // dh^-0.5 * log2(e)

  f16x8 qf0, qf1;
  {
    const f16* qp = Q + ((size_t)(b * 2048 + qrow0 + l15)) * 1024 + h * 64;
    qf0 = *reinterpret_cast<const f16x8*>(qp + l4 * 8);
    qf1 = *reinterpret_cast<const f16x8*>(qp + 32 + l4 * 8);
  }
  f32x4 acc[4] = {};
  float mst[4] = {-1e30f, -1e30f, -1e30f, -1e30f};
  float lst[4] = {0.f, 0.f, 0.f, 0.f};

  int nkv = qb + 1;
  int ekv = (E + 63) >> 6;
  if (ekv > nkv) nkv = ekv;
  if (nkv > 32) nkv = 32;

  auto LOADK = [&](int jb, f16x8* k0, f16x8* k1) {
#pragma unroll
    for (int jt = 0; jt < 4; ++jt) {
      const f16* kp = Kg + ((size_t)(b * 2048 + jb * 64 + jt * 16 + l15)) * 1024 + h * 64;
      k0[jt] = *reinterpret_cast<const f16x8*>(kp + l4 * 8);
      k1[jt] = *reinterpret_cast<const f16x8*>(kp + 32 + l4 * 8);
    }
  };

  auto BODY = [&](int jb, const f16x8* kc0, const f16x8* kc1,
                  f16x8* kn0, f16x8* kn1, int pb) {
    // QK^T for this kv tile
    f32x4 sc[4];
#pragma unroll
    for (int jt = 0; jt < 4; ++jt) {
      f32x4 s = {};
      s = __builtin_amdgcn_mfma_f32_16x16x32_f16(qf0, kc0[jt], s, 0, 0, 0);
      s = __builtin_amdgcn_mfma_f32_16x16x32_f16(qf1, kc1[jt], s, 0, 0, 0);
      sc[jt] = s;
    }
    // issue V + amask loads now (consumed after softmax -> latency hidden)
    f16x8 vb0[4], vb1[4];
#pragma unroll
    for (int dt = 0; dt < 4; ++dt) {
      const f16* vp = Vt + (size_t)bh * 131072 + (size_t)(dt * 16 + l15) * 2048 + jb * 64;
      vb0[dt] = *reinterpret_cast<const f16x8*>(vp + l4 * 8);
      vb1[dt] = *reinterpret_cast<const f16x8*>(vp + 32 + l4 * 8);
    }
    int am[4];
#pragma unroll
    for (int jt = 0; jt < 4; ++jt)
      am[jt] = amask[b * 2048 + jb * 64 + jt * 16 + l15];
    // prefetch next K tile into the other register set
    int jn = (jb + 1 < nkv) ? jb + 1 : jb;
    LOADK(jn, kn0, kn1);
    // mask + scale (log2 domain)
#pragma unroll
    for (int jt = 0; jt < 4; ++jt) {
      int jcol = jb * 64 + jt * 16 + l15;
      bool colok = (am[jt] != 0);
#pragma unroll
      for (int r = 0; r < 4; ++r) {
        int irow = qrow0 + l4 * 4 + r;
        bool vis = colok && ((jcol <= irow) || (jcol < E));
        sc[jt][r] = vis ? sc[jt][r] * SCALE : -1e30f;
      }
    }
    // online softmax (rows span 16 l15-lanes within each l4 group)
#pragma unroll
    for (int r = 0; r < 4; ++r) {
      float m = fmaxf(fmaxf(sc[0][r], sc[1][r]), fmaxf(sc[2][r], sc[3][r]));
#pragma unroll
      for (int off = 1; off < 16; off <<= 1) m = fmaxf(m, __shfl_xor(m, off, 64));
      float mnew = fmaxf(mst[r], m);
      float alpha = (mnew <= -1e29f) ? 0.f : exp2f(mst[r] - mnew);
      float psum = 0.f;
      int prow = l4 * 4 + r;
#pragma unroll
      for (int jt = 0; jt < 4; ++jt) {
        float sv = sc[jt][r];
        float p = (sv <= -1e29f) ? 0.f : exp2f(sv - mnew);
        psum += p;
        int pcol = jt * 16 + l15;
        P_lds[wave][pb][prow * 64 + (((pcol >> 3) ^ (prow & 7)) << 3) + (pcol & 7)] = (f16)p;
      }
#pragma unroll
      for (int off = 1; off < 16; off <<= 1) psum += __shfl_xor(psum, off, 64);
      lst[r] = lst[r] * alpha + psum;
      mst[r] = mnew;
#pragma unroll
      for (int dt = 0; dt < 4; ++dt) acc[dt][r] *= alpha;
    }
    // wave-private P roundtrip: wait LDS writes, then read A-fragments
    asm volatile("s_waitcnt lgkmcnt(0)" ::: "memory");
    __builtin_amdgcn_sched_barrier(0);
    f16x8 pa0 = *reinterpret_cast<const f16x8*>(
        &P_lds[wave][pb][l15 * 64 + ((l4 ^ (l15 & 7)) << 3)]);
    f16x8 pa1 = *reinterpret_cast<const f16x8*>(
        &P_lds[wave][pb][l15 * 64 + (((4 + l4) ^ (l15 & 7)) << 3)]);
#pragma unroll
    for (int dt = 0; dt < 4; ++dt) {
      acc[dt] = __builtin_amdgcn_mfma_f32_16x16x32_f16(pa0, vb0[dt], acc[dt], 0, 0, 0);
      acc[dt] = __builtin_amdgcn_mfma_f32_16x16x32_f16(pa1, vb1[dt], acc[dt], 0, 0, 0);
    }
  };

  f16x8 kA0[4], kA1[4], kB0[4], kB1[4];
  LOADK(0, kA0, kA1);
  int jb = 0, pb = 0;
  while (true) {
    BODY(jb, kA0, kA1, kB0, kB1, pb);
    if (++jb >= nkv) break;
    pb ^= 1;
    BODY(jb, kB0, kB1, kA0, kA1, pb);
    if (++jb >= nkv) break;
    pb ^= 1;
  }

#pragma unroll
  for (int r = 0; r < 4; ++r) {
    float inv = 1.0f / lst[r];
    int row = qrow0 + l4 * 4 + r;
    f16* op = AO + ((size_t)(b * 2048 + row)) * 1024 + h * 64;
#pragma unroll
    for (int dt = 0; dt < 4; ++dt)
      op[dt * 16 + l15] = (f16)(acc[dt][r] * inv);
  }
}

// ---------------- launcher ----------------
extern "C" void kernel_launch(void* const* d_in, const int* in_sizes, int n_in,
                              void* d_out, int out_size, void* d_ws, size_t ws_size,
                              hipStream_t stream) {
  const float* x  = (const float*)d_in[0];
  const float* Wq = (const float*)d_in[1];
  const float* Wk = (const float*)d_in[2];
  const float* Wv = (const float*)d_in[3];
  const float* Wo = (const float*)d_in[4];
  const int* amask = (const int*)d_in[5];
  const int* pE    = (const int*)d_in[6];
  const int* pSkip = (const int*)d_in[7];

  char* ws = (char*)d_ws;
  f16* xb  = (f16*)(ws);
  f16* Wqb = (f16*)(ws + (16u << 20));
  f16* Wkb = (f16*)(ws + (18u << 20));
  f16* Wvb = (f16*)(ws + (20u << 20));
  f16* Wob = (f16*)(ws + (22u << 20));
  f16* Qf  = (f16*)(ws + (24u << 20));
  f16* Kf  = (f16*)(ws + (40u << 20));
  f16* Vf  = (f16*)(ws + (56u << 20));
  f16* Vt  = (f16*)(ws + (72u << 20));
  f16* AO  = xb;

  k_cvt<<<4096, 256, 0, stream>>>(x, xb, 8388608);
  k_cvt<<<512, 256, 0, stream>>>(Wq, Wqb, 1048576);
  k_cvt<<<512, 256, 0, stream>>>(Wk, Wkb, 1048576);
  k_cvt<<<512, 256, 0, stream>>>(Wv, Wvb, 1048576);
  k_cvt<<<512, 256, 0, stream>>>(Wo, Wob, 1048576);
  k_gemm<0><<<dim3(8, 64, 3), 256, 0, stream>>>(xb, Wqb, Wkb, Wvb, Qf, Kf, Vf);
  k_rope<<<16384, 256, 0, stream>>>(Qf, Kf, pE, pSkip);
  k_vtrans<<<dim3(32, 64), 256, 0, stream>>>(Vf, Vt);
  k_attn<<<2048, 256, 0, stream>>>(Qf, Kf, Vt, amask, pE, AO);
  k_gemm<1><<<dim3(8, 64, 1), 256, 0, stream>>>(AO, Wob, Wob, Wob, d_out, d_out, d_out);
}